// Round 1
// baseline (598.127 us; speedup 1.0000x reference)
//
#include <hip/hip_runtime.h>

#define N_NODES 80000
#define N_EDGES 1280000
#define F_IN 64
#define F_HID 128
#define F_OUT 40

// -------- SPMM1: h1[src[e]][f] += vals[e] * x[dst[e]][f], f in [0,64) --------
// One 64-lane wave per edge; lane = feature. Coalesced 256B row gather.
__global__ __launch_bounds__(256) void spmm64_kernel(
    const int* __restrict__ src, const int* __restrict__ dst,
    const float* __restrict__ vals, const float* __restrict__ x,
    float* __restrict__ out) {
  int gid = blockIdx.x * 256 + threadIdx.x;
  int e = gid >> 6;
  int f = gid & 63;
  if (e >= N_EDGES) return;
  int s = src[e];
  int d = dst[e];
  float v = vals[e];
  atomicAdd(&out[s * F_IN + f], v * x[d * F_IN + f]);
}

// -------- Fused dense: g = relu(h1 @ W1) @ W2, per 32-row block --------
__global__ __launch_bounds__(256) void dense_fused_kernel(
    const float* __restrict__ h1, const float* __restrict__ W1,
    const float* __restrict__ W2, float* __restrict__ g) {
  __shared__ float sW1[F_IN * F_HID];    // 32 KB
  __shared__ float sW2[F_HID * F_OUT];   // 20 KB
  __shared__ float sX[32 * F_IN];        // 8 KB
  __shared__ float sH[32 * F_HID];       // 16 KB
  int tid = threadIdx.x;
  int rbase = blockIdx.x * 32;

  for (int i = tid; i < F_IN * F_HID; i += 256) sW1[i] = W1[i];
  for (int i = tid; i < F_HID * F_OUT; i += 256) sW2[i] = W2[i];
  for (int i = tid; i < 32 * F_IN; i += 256) {
    int r = i >> 6;
    int k = i & 63;
    sX[i] = h1[(rbase + r) * F_IN + k];
  }
  __syncthreads();

  // phase 1: sH = relu(sX @ W1). 32x128 outputs, 16 per thread.
  {
    int c = tid & 127;
    int r0 = (tid >> 7) * 16;
    float acc[16];
#pragma unroll
    for (int i = 0; i < 16; i++) acc[i] = 0.f;
    for (int k = 0; k < F_IN; k++) {
      float w = sW1[k * F_HID + c];
#pragma unroll
      for (int i = 0; i < 16; i++) acc[i] += sX[(r0 + i) * F_IN + k] * w;
    }
#pragma unroll
    for (int i = 0; i < 16; i++) sH[(r0 + i) * F_HID + c] = fmaxf(acc[i], 0.f);
  }
  __syncthreads();

  // phase 2: g = sH @ W2. 32x40 = 1280 outputs, 5 per thread.
#pragma unroll
  for (int i = 0; i < 5; i++) {
    int o = tid + 256 * i;
    int r = o / F_OUT;
    int c = o % F_OUT;
    float acc = 0.f;
    for (int k = 0; k < F_HID; k++) acc += sH[r * F_HID + k] * sW2[k * F_OUT + c];
    g[(rbase + r) * F_OUT + c] = acc;
  }
}

// -------- SPMM2: out[src[e]][f] += vals[e] * g[dst[e]][f], f in [0,40) --------
__global__ __launch_bounds__(256) void spmm40_kernel(
    const int* __restrict__ src, const int* __restrict__ dst,
    const float* __restrict__ vals, const float* __restrict__ g,
    float* __restrict__ out) {
  int gid = blockIdx.x * 256 + threadIdx.x;
  if (gid >= N_EDGES * F_OUT) return;
  int e = gid / F_OUT;
  int f = gid - e * F_OUT;
  int s = src[e];
  int d = dst[e];
  atomicAdd(&out[s * F_OUT + f], vals[e] * g[d * F_OUT + f]);
}

extern "C" void kernel_launch(void* const* d_in, const int* in_sizes, int n_in,
                              void* d_out, int out_size, void* d_ws, size_t ws_size,
                              hipStream_t stream) {
  const int* src = (const int*)d_in[0];
  const int* dst = (const int*)d_in[1];
  const float* vals = (const float*)d_in[2];
  const float* x = (const float*)d_in[3];
  const float* W1 = (const float*)d_in[4];
  const float* W2 = (const float*)d_in[5];
  float* out = (float*)d_out;

  float* h1 = (float*)d_ws;                       // N*64 floats = 20.48 MB
  float* g = h1 + (size_t)N_NODES * F_IN;         // N*40 floats = 12.80 MB

  hipMemsetAsync(h1, 0, (size_t)N_NODES * F_IN * sizeof(float), stream);

  {
    int total = N_EDGES * 64;
    spmm64_kernel<<<total / 256, 256, 0, stream>>>(src, dst, vals, x, h1);
  }

  dense_fused_kernel<<<N_NODES / 32, 256, 0, stream>>>(h1, W1, W2, g);

  hipMemsetAsync(out, 0, (size_t)N_NODES * F_OUT * sizeof(float), stream);

  {
    long long total = (long long)N_EDGES * F_OUT;
    int blocks = (int)((total + 255) / 256);
    spmm40_kernel<<<blocks, 256, 0, stream>>>(src, dst, vals, g, out);
  }
}

// Round 3
// 436.967 us; speedup vs baseline: 1.3688x; 1.3688x over previous
//
#include <hip/hip_runtime.h>

#define N_NODES 80000
#define N_EDGES 1280000
#define F_IN 64
#define F_HID 128
#define F_OUT 40

// ---------------- CSR build: histogram ----------------
__global__ __launch_bounds__(256) void hist_kernel(const int* __restrict__ src,
                                                   int* __restrict__ deg) {
  int i = blockIdx.x * 256 + threadIdx.x;
  if (i < N_EDGES) atomicAdd(&deg[src[i]], 1);
}

// ---------------- CSR build: single-block scan ----------------
__global__ __launch_bounds__(1024) void scan_kernel(const int* __restrict__ deg,
                                                    int* __restrict__ rs,
                                                    int* __restrict__ cur) {
  __shared__ int wsum[16];
  __shared__ int woff[16];
  __shared__ int carry_s;
  int tid = threadIdx.x;
  int lane = tid & 63, wid = tid >> 6;
  if (tid == 0) carry_s = 0;
  __syncthreads();
  for (int base = 0; base < N_NODES; base += 1024) {
    int i = base + tid;
    int v = (i < N_NODES) ? deg[i] : 0;
    int s = v;
#pragma unroll
    for (int off = 1; off < 64; off <<= 1) {
      int t = __shfl_up(s, off, 64);
      if (lane >= off) s += t;
    }
    if (lane == 63) wsum[wid] = s;
    __syncthreads();              // wsum ready
    int carry = carry_s;
    __syncthreads();              // all read old carry
    if (wid == 0) {
      int wv = (lane < 16) ? wsum[lane] : 0;
      int ss = wv;
#pragma unroll
      for (int off = 1; off < 16; off <<= 1) {
        int t = __shfl_up(ss, off, 64);
        if (lane >= off) ss += t;
      }
      if (lane < 16) woff[lane] = ss - wv;   // exclusive wave offsets
      if (lane == 15) carry_s = carry + ss;  // new running total
    }
    __syncthreads();              // woff, carry_s ready
    int excl = carry + woff[wid] + (s - v);
    if (i < N_NODES) { rs[i] = excl; cur[i] = excl; }
    __syncthreads();              // protect wsum for next chunk
  }
  if (tid == 0) rs[N_NODES] = carry_s;
}

// ---------------- CSR build: scatter edges into slots ----------------
__global__ __launch_bounds__(256) void scatter_kernel(
    const int* __restrict__ src, const int* __restrict__ dst,
    const float* __restrict__ vals, int* __restrict__ cur,
    int* __restrict__ edst, float* __restrict__ eval) {
  int i = blockIdx.x * 256 + threadIdx.x;
  if (i < N_EDGES) {
    int s = src[i];
    int p = atomicAdd(&cur[s], 1);
    edst[p] = dst[i];
    eval[p] = vals[i];
  }
}

// ---- Fused: rows = gather(A, x) in LDS, then g = relu(rows@W1)@W2 ----
// 512 threads = 8 waves; 32 rows per block; each wave gathers 4 rows.
__global__ __launch_bounds__(512) void spmm_dense_kernel(
    const int* __restrict__ rs, const int* __restrict__ edst,
    const float* __restrict__ eval, const float* __restrict__ x,
    const float* __restrict__ W1, const float* __restrict__ W2,
    float* __restrict__ g) {
  __shared__ float sW1[F_IN * F_HID];    // 32 KB
  __shared__ float sW2[F_HID * F_OUT];   // 20 KB
  __shared__ float sX[32 * F_IN];        // 8 KB
  __shared__ float sH[32 * F_HID];       // 16 KB
  int tid = threadIdx.x, lane = tid & 63, wid = tid >> 6;
  int rbase = blockIdx.x * 32;

  for (int i = tid; i < F_IN * F_HID; i += 512) sW1[i] = W1[i];
  for (int i = tid; i < F_HID * F_OUT; i += 512) sW2[i] = W2[i];

  // gather A@x rows (64 feats, lane = feature), 4 rows per wave
#pragma unroll
  for (int r = 0; r < 4; ++r) {
    int node = rbase + wid * 4 + r;
    int j0 = rs[node], j1 = rs[node + 1];
    float acc = 0.f;
    int j = j0;
    for (; j + 4 <= j1; j += 4) {
      int d0 = edst[j], d1 = edst[j + 1], d2 = edst[j + 2], d3 = edst[j + 3];
      float v0 = eval[j], v1 = eval[j + 1], v2 = eval[j + 2], v3 = eval[j + 3];
      float x0 = x[(size_t)d0 * F_IN + lane];
      float x1 = x[(size_t)d1 * F_IN + lane];
      float x2 = x[(size_t)d2 * F_IN + lane];
      float x3 = x[(size_t)d3 * F_IN + lane];
      acc += v0 * x0;
      acc += v1 * x1;
      acc += v2 * x2;
      acc += v3 * x3;
    }
    for (; j < j1; ++j) acc += eval[j] * x[(size_t)edst[j] * F_IN + lane];
    sX[(wid * 4 + r) * F_IN + lane] = acc;
  }
  __syncthreads();

  // phase 1: sH = relu(sX @ sW1). 32x128 outputs, 8 per thread.
  {
    int c = tid & 127;
    int r0 = (tid >> 7) * 8;
    float acc[8];
#pragma unroll
    for (int i = 0; i < 8; ++i) acc[i] = 0.f;
    for (int k = 0; k < F_IN; ++k) {
      float w = sW1[k * F_HID + c];
#pragma unroll
      for (int i = 0; i < 8; ++i) acc[i] += sX[(r0 + i) * F_IN + k] * w;
    }
#pragma unroll
    for (int i = 0; i < 8; ++i) sH[(r0 + i) * F_HID + c] = fmaxf(acc[i], 0.f);
  }
  __syncthreads();

  // phase 2: g = sH @ sW2. 32x40 outputs.
  for (int o = tid; o < 32 * F_OUT; o += 512) {
    int r = o / F_OUT, c = o - r * F_OUT;
    float acc = 0.f;
    for (int k = 0; k < F_HID; ++k)
      acc += sH[r * F_HID + k] * sW2[k * F_OUT + c];
    g[(size_t)(rbase + r) * F_OUT + c] = acc;
  }
}

// ---------------- SPMM2 gather: out = A @ g (40 feats) ----------------
__global__ __launch_bounds__(256) void spmm2_kernel(
    const int* __restrict__ rs, const int* __restrict__ edst,
    const float* __restrict__ eval, const float* __restrict__ g,
    float* __restrict__ out) {
  int node = (blockIdx.x * 256 + threadIdx.x) >> 6;
  int lane = threadIdx.x & 63;
  if (node >= N_NODES || lane >= F_OUT) return;
  int j0 = rs[node], j1 = rs[node + 1];
  float acc = 0.f;
  int j = j0;
  for (; j + 4 <= j1; j += 4) {
    int d0 = edst[j], d1 = edst[j + 1], d2 = edst[j + 2], d3 = edst[j + 3];
    float v0 = eval[j], v1 = eval[j + 1], v2 = eval[j + 2], v3 = eval[j + 3];
    float g0 = g[(size_t)d0 * F_OUT + lane];
    float g1 = g[(size_t)d1 * F_OUT + lane];
    float g2 = g[(size_t)d2 * F_OUT + lane];
    float g3 = g[(size_t)d3 * F_OUT + lane];
    acc += v0 * g0;
    acc += v1 * g1;
    acc += v2 * g2;
    acc += v3 * g3;
  }
  for (; j < j1; ++j) acc += eval[j] * g[(size_t)edst[j] * F_OUT + lane];
  out[(size_t)node * F_OUT + lane] = acc;
}

extern "C" void kernel_launch(void* const* d_in, const int* in_sizes, int n_in,
                              void* d_out, int out_size, void* d_ws, size_t ws_size,
                              hipStream_t stream) {
  const int* src = (const int*)d_in[0];
  const int* dst = (const int*)d_in[1];
  const float* vals = (const float*)d_in[2];
  const float* x = (const float*)d_in[3];
  const float* W1 = (const float*)d_in[4];
  const float* W2 = (const float*)d_in[5];
  float* out = (float*)d_out;

  int* deg = (int*)d_ws;                 // 80000
  int* rs = deg + N_NODES;               // 80001
  int* cur = rs + (N_NODES + 1);         // 80000
  int* edst = cur + N_NODES;             // 1280000
  float* eval = (float*)(edst + N_EDGES);// 1280000
  float* g = eval + N_EDGES;             // 3200000  (total ~24 MB)

  hipMemsetAsync(deg, 0, N_NODES * sizeof(int), stream);

  hist_kernel<<<(N_EDGES + 255) / 256, 256, 0, stream>>>(src, deg);
  scan_kernel<<<1, 1024, 0, stream>>>(deg, rs, cur);
  scatter_kernel<<<(N_EDGES + 255) / 256, 256, 0, stream>>>(src, dst, vals, cur,
                                                            edst, eval);
  spmm_dense_kernel<<<N_NODES / 32, 512, 0, stream>>>(rs, edst, eval, x, W1, W2, g);
  spmm2_kernel<<<(N_NODES * 64 + 255) / 256, 256, 0, stream>>>(rs, edst, eval, g, out);
}

// Round 4
// 342.565 us; speedup vs baseline: 1.7460x; 1.2756x over previous
//
#include <hip/hip_runtime.h>

#define N_NODES 80000
#define N_EDGES 1280000
#define F_IN 64
#define F_HID 128
#define F_OUT 40

// ---------------- CSR build: histogram ----------------
__global__ __launch_bounds__(256) void hist_kernel(const int* __restrict__ src,
                                                   int* __restrict__ deg) {
  int i = blockIdx.x * 256 + threadIdx.x;
  if (i < N_EDGES) atomicAdd(&deg[src[i]], 1);
}

// ------- CSR build: single-block scan, 4 nodes per thread (int4) -------
__global__ __launch_bounds__(1024) void scan_kernel(const int4* __restrict__ deg4,
                                                    int* __restrict__ rs,
                                                    int* __restrict__ cur) {
  __shared__ int wsum[16];
  __shared__ int woff[16];
  __shared__ int carry_s;
  int tid = threadIdx.x;
  int lane = tid & 63, wid = tid >> 6;
  if (tid == 0) carry_s = 0;
  __syncthreads();
  const int NQ = N_NODES / 4;  // 20000
  for (int base = 0; base < NQ; base += 1024) {
    int i = base + tid;
    int4 v = (i < NQ) ? deg4[i] : make_int4(0, 0, 0, 0);
    int tot = v.x + v.y + v.z + v.w;
    int s = tot;
#pragma unroll
    for (int off = 1; off < 64; off <<= 1) {
      int t = __shfl_up(s, off, 64);
      if (lane >= off) s += t;
    }
    if (lane == 63) wsum[wid] = s;
    __syncthreads();              // wsum ready
    int carry = carry_s;
    __syncthreads();              // all read old carry
    if (wid == 0) {
      int wv = (lane < 16) ? wsum[lane] : 0;
      int ss = wv;
#pragma unroll
      for (int off = 1; off < 16; off <<= 1) {
        int t = __shfl_up(ss, off, 64);
        if (lane >= off) ss += t;
      }
      if (lane < 16) woff[lane] = ss - wv;   // exclusive wave offsets
      if (lane == 15) carry_s = carry + ss;  // new running total
    }
    __syncthreads();              // woff, carry_s ready
    int excl = carry + woff[wid] + (s - tot);
    if (i < NQ) {
      int e0 = excl, e1 = e0 + v.x, e2 = e1 + v.y, e3 = e2 + v.z;
      int4 r = make_int4(e0, e1, e2, e3);
      ((int4*)rs)[i] = r;
      ((int4*)cur)[i] = r;
    }
    __syncthreads();              // protect wsum/carry for next chunk
  }
  if (tid == 0) rs[N_NODES] = carry_s;
}

// ---------------- CSR build: scatter packed (dst,val) ----------------
__global__ __launch_bounds__(256) void scatter_kernel(
    const int* __restrict__ src, const int* __restrict__ dst,
    const float* __restrict__ vals, int* __restrict__ cur,
    int2* __restrict__ epack) {
  int i = blockIdx.x * 256 + threadIdx.x;
  if (i < N_EDGES) {
    int p = atomicAdd(&cur[src[i]], 1);
    epack[p] = make_int2(dst[i], __float_as_int(vals[i]));
  }
}

// ---- Fused: rows = gather(A, x) in LDS, then g = relu(rows@W1)@W2 ----
// 512 threads = 8 waves; 32 rows per block; wave gathers 4 rows.
// Gather: lane = (edge-slot h, feature-pair fi): 2 edges per step, float2 loads.
__global__ __launch_bounds__(512, 6) void spmm_dense_kernel(
    const int* __restrict__ rs, const int2* __restrict__ epack,
    const float* __restrict__ x, const float* __restrict__ W1,
    const float* __restrict__ W2, float* __restrict__ g) {
  __shared__ float sX[32 * F_IN];    // 8 KB
  __shared__ float sH[32 * F_HID];   // 16 KB
  int tid = threadIdx.x, lane = tid & 63, wid = tid >> 6;
  int rbase = blockIdx.x * 32;
  int h = lane >> 5;     // which of 2 parallel edges
  int fi = lane & 31;    // feature-pair index (features 2fi, 2fi+1)

#pragma unroll
  for (int r = 0; r < 4; ++r) {
    int node = rbase + wid * 4 + r;
    int j0 = rs[node], j1 = rs[node + 1];
    float accx = 0.f, accy = 0.f;
    int j = j0;
    for (; j + 8 <= j1; j += 8) {   // 8 edges in flight
      int2 e0 = epack[j + h];
      int2 e1 = epack[j + 2 + h];
      int2 e2 = epack[j + 4 + h];
      int2 e3 = epack[j + 6 + h];
      float2 x0 = *(const float2*)&x[(size_t)e0.x * F_IN + fi * 2];
      float2 x1 = *(const float2*)&x[(size_t)e1.x * F_IN + fi * 2];
      float2 x2 = *(const float2*)&x[(size_t)e2.x * F_IN + fi * 2];
      float2 x3 = *(const float2*)&x[(size_t)e3.x * F_IN + fi * 2];
      float v0 = __int_as_float(e0.y), v1 = __int_as_float(e1.y);
      float v2 = __int_as_float(e2.y), v3 = __int_as_float(e3.y);
      accx += v0 * x0.x; accy += v0 * x0.y;
      accx += v1 * x1.x; accy += v1 * x1.y;
      accx += v2 * x2.x; accy += v2 * x2.y;
      accx += v3 * x3.x; accy += v3 * x3.y;
    }
    for (; j + 2 <= j1; j += 2) {
      int2 e = epack[j + h];
      float2 xx = *(const float2*)&x[(size_t)e.x * F_IN + fi * 2];
      float v = __int_as_float(e.y);
      accx += v * xx.x; accy += v * xx.y;
    }
    if (j < j1 && h == 0) {         // odd tail edge
      int2 e = epack[j];
      float2 xx = *(const float2*)&x[(size_t)e.x * F_IN + fi * 2];
      float v = __int_as_float(e.y);
      accx += v * xx.x; accy += v * xx.y;
    }
    accx += __shfl_xor(accx, 32, 64);
    accy += __shfl_xor(accy, 32, 64);
    if (h == 0) {
      float2 o; o.x = accx; o.y = accy;
      *(float2*)&sX[(wid * 4 + r) * F_IN + fi * 2] = o;
    }
  }
  __syncthreads();

  // phase 1: sH = relu(sX @ W1); W1 streamed from global (L1/L2-resident).
  {
    int c = tid & 127;
    int r0 = (tid >> 7) * 8;
    float acc[8];
#pragma unroll
    for (int i = 0; i < 8; ++i) acc[i] = 0.f;
    for (int k = 0; k < F_IN; ++k) {
      float w = W1[k * F_HID + c];
#pragma unroll
      for (int i = 0; i < 8; ++i) acc[i] += sX[(r0 + i) * F_IN + k] * w;
    }
#pragma unroll
    for (int i = 0; i < 8; ++i) sH[(r0 + i) * F_HID + c] = fmaxf(acc[i], 0.f);
  }
  __syncthreads();

  // phase 2: g = sH @ W2; W2 from global.
  for (int o = tid; o < 32 * F_OUT; o += 512) {
    int r = o / F_OUT, c = o - r * F_OUT;
    float acc = 0.f;
    for (int k = 0; k < F_HID; ++k)
      acc += sH[r * F_HID + k] * W2[k * F_OUT + c];
    g[(size_t)(rbase + r) * F_OUT + c] = acc;
  }
}

// ------- SPMM2 gather: out = A @ g (40 feats), 3 edges per wave-step -------
__global__ __launch_bounds__(256) void spmm2_kernel(
    const int* __restrict__ rs, const int2* __restrict__ epack,
    const float* __restrict__ g, float* __restrict__ out) {
  int node = (blockIdx.x * 256 + threadIdx.x) >> 6;
  int lane = threadIdx.x & 63;
  if (node >= N_NODES) return;
  int grp = lane / 20;        // 0..2 live, 3 = idle (lanes 60-63)
  int fi = lane % 20;         // feature pair (features 2fi, 2fi+1)
  bool active = lane < 60;
  int j0 = rs[node], j1 = rs[node + 1];
  float accx = 0.f, accy = 0.f;
  int j = j0;
  for (; j + 6 <= j1; j += 6) {   // 6 edges in flight
    if (active) {
      int2 ea = epack[j + grp];
      int2 eb = epack[j + 3 + grp];
      float2 ga = *(const float2*)&g[(size_t)ea.x * F_OUT + fi * 2];
      float2 gb = *(const float2*)&g[(size_t)eb.x * F_OUT + fi * 2];
      float va = __int_as_float(ea.y), vb = __int_as_float(eb.y);
      accx += va * ga.x; accy += va * ga.y;
      accx += vb * gb.x; accy += vb * gb.y;
    }
  }
  for (; j + 3 <= j1; j += 3) {
    if (active) {
      int2 e = epack[j + grp];
      float2 gg = *(const float2*)&g[(size_t)e.x * F_OUT + fi * 2];
      float v = __int_as_float(e.y);
      accx += v * gg.x; accy += v * gg.y;
    }
  }
  int rem = j1 - j;               // 0..2
  if (active && grp < rem) {
    int2 e = epack[j + grp];
    float2 gg = *(const float2*)&g[(size_t)e.x * F_OUT + fi * 2];
    float v = __int_as_float(e.y);
    accx += v * gg.x; accy += v * gg.y;
  }
  // merge the 3 groups into lanes 0-19
  float tx = __shfl(accx, lane + 40, 64);
  float ty = __shfl(accy, lane + 40, 64);
  if (lane < 20) { accx += tx; accy += ty; }
  tx = __shfl(accx, lane + 20, 64);
  ty = __shfl(accy, lane + 20, 64);
  if (lane < 20) {
    accx += tx; accy += ty;
    float2 o; o.x = accx; o.y = accy;
    *(float2*)&out[(size_t)node * F_OUT + fi * 2] = o;
  }
}

extern "C" void kernel_launch(void* const* d_in, const int* in_sizes, int n_in,
                              void* d_out, int out_size, void* d_ws, size_t ws_size,
                              hipStream_t stream) {
  const int* src = (const int*)d_in[0];
  const int* dst = (const int*)d_in[1];
  const float* vals = (const float*)d_in[2];
  const float* x = (const float*)d_in[3];
  const float* W1 = (const float*)d_in[4];
  const float* W2 = (const float*)d_in[5];
  float* out = (float*)d_out;

  int* deg = (int*)d_ws;                        // 80000
  int* rs = deg + N_NODES;                      // 80001
  int* cur = rs + (N_NODES + 1);                // 80000
  int2* epack = (int2*)((char*)d_ws + 240002 * sizeof(int));  // 8B aligned
  float* g = (float*)(epack + N_EDGES);         // 3.2M floats

  hipMemsetAsync(deg, 0, N_NODES * sizeof(int), stream);

  hist_kernel<<<(N_EDGES + 255) / 256, 256, 0, stream>>>(src, deg);
  scan_kernel<<<1, 1024, 0, stream>>>((const int4*)deg, rs, cur);
  scatter_kernel<<<(N_EDGES + 255) / 256, 256, 0, stream>>>(src, dst, vals, cur, epack);
  spmm_dense_kernel<<<N_NODES / 32, 512, 0, stream>>>(rs, epack, x, W1, W2, g);
  spmm2_kernel<<<(N_NODES * 64 + 255) / 256, 256, 0, stream>>>(rs, epack, g, out);
}

// Round 8
// 304.455 us; speedup vs baseline: 1.9646x; 1.1252x over previous
//
#include <hip/hip_runtime.h>

#define N_NODES 80000
#define N_EDGES 1280000
#define F_IN 64
#define F_HID 128
#define F_OUT 40
#define NQ (N_NODES / 4)   // 20000 int4 groups
#define SHP 129            // padded sH stride (kills bank conflicts)

// ---------------- CSR build: histogram ----------------
__global__ __launch_bounds__(256) void hist_kernel(const int* __restrict__ src,
                                                   int* __restrict__ deg) {
  int i = blockIdx.x * 256 + threadIdx.x;
  if (i < N_EDGES) atomicAdd(&deg[src[i]], 1);
}

// ------- scan A: 20 blocks, block-local exclusive scan + block sums -------
__global__ __launch_bounds__(1024) void scanA_kernel(const int4* __restrict__ deg4,
                                                     int4* __restrict__ rs4,
                                                     int* __restrict__ bsum) {
  __shared__ int wsum[16];
  __shared__ int woff[16];
  int tid = threadIdx.x, lane = tid & 63, wid = tid >> 6;
  int i = blockIdx.x * 1024 + tid;
  int4 v = (i < NQ) ? deg4[i] : make_int4(0, 0, 0, 0);
  int tot = v.x + v.y + v.z + v.w;
  int s = tot;
#pragma unroll
  for (int off = 1; off < 64; off <<= 1) {
    int t = __shfl_up(s, off, 64);
    if (lane >= off) s += t;
  }
  if (lane == 63) wsum[wid] = s;
  __syncthreads();
  if (wid == 0) {
    int wv = (lane < 16) ? wsum[lane] : 0;
    int ss = wv;
#pragma unroll
    for (int off = 1; off < 16; off <<= 1) {
      int t = __shfl_up(ss, off, 64);
      if (lane >= off) ss += t;
    }
    if (lane < 16) woff[lane] = ss - wv;
    if (lane == 15) bsum[blockIdx.x] = ss;
  }
  __syncthreads();
  int excl = woff[wid] + (s - tot);
  if (i < NQ) {
    int e0 = excl, e1 = e0 + v.x, e2 = e1 + v.y, e3 = e2 + v.z;
    rs4[i] = make_int4(e0, e1, e2, e3);
  }
}

// ------- scan B: 1 tiny block scans the 20 block sums -------
__global__ __launch_bounds__(64) void scanB_kernel(const int* __restrict__ bsum,
                                                   int* __restrict__ boff,
                                                   int* __restrict__ rs) {
  int lane = threadIdx.x;
  int v = (lane < 20) ? bsum[lane] : 0;
  int s = v;
#pragma unroll
  for (int off = 1; off < 32; off <<= 1) {
    int t = __shfl_up(s, off, 64);
    if (lane >= off) s += t;
  }
  if (lane < 20) boff[lane] = s - v;
  if (lane == 19) rs[N_NODES] = s;   // grand total
}

// ------- scan C: add block offsets, write rs and cur -------
__global__ __launch_bounds__(1024) void scanC_kernel(int4* __restrict__ rs4,
                                                     int4* __restrict__ cur4,
                                                     const int* __restrict__ boff) {
  int i = blockIdx.x * 1024 + threadIdx.x;
  if (i < NQ) {
    int o = boff[blockIdx.x];
    int4 r = rs4[i];
    r.x += o; r.y += o; r.z += o; r.w += o;
    rs4[i] = r;
    cur4[i] = r;
  }
}

// ---------------- CSR build: scatter packed (dst,val) ----------------
__global__ __launch_bounds__(256) void scatter_kernel(
    const int* __restrict__ src, const int* __restrict__ dst,
    const float* __restrict__ vals, int* __restrict__ cur,
    int2* __restrict__ epack) {
  int i = blockIdx.x * 256 + threadIdx.x;
  if (i < N_EDGES) {
    int p = atomicAdd(&cur[src[i]], 1);
    epack[p] = make_int2(dst[i], __float_as_int(vals[i]));
  }
}

// ---- Fused: rows = gather(A, x) in LDS, then g = relu(rows@W1)@W2 ----
// 512 threads = 8 waves; 32 rows/block; wave gathers 4 rows.
// Gather lanes: fi = lane&15 (float4 feature quad), h = lane>>4 (4 edges/step).
__global__ __launch_bounds__(512, 6) void spmm_dense_kernel(
    const int* __restrict__ rs, const int2* __restrict__ epack,
    const float* __restrict__ x, const float* __restrict__ W1,
    const float* __restrict__ W2, float* __restrict__ g) {
  __shared__ float sX[32 * F_IN];     // 8 KB
  __shared__ float sH[32 * SHP];      // 16.1 KB (padded)
  int tid = threadIdx.x, lane = tid & 63, wid = tid >> 6;
  int rbase = blockIdx.x * 32;
  int h = lane >> 4;     // 0..3: which of 4 parallel edges
  int fi = lane & 15;    // feature-quad index (feats 4fi..4fi+3)

#pragma unroll
  for (int r = 0; r < 4; ++r) {
    int node = rbase + wid * 4 + r;
    int j0 = rs[node], j1 = rs[node + 1];
    float ax = 0.f, ay = 0.f, az = 0.f, aw = 0.f;
    int j = j0;
    for (; j + 8 <= j1; j += 8) {     // 8 edges in flight
      int2 e0 = epack[j + h];
      int2 e1 = epack[j + 4 + h];
      float4 x0 = *(const float4*)&x[(size_t)e0.x * F_IN + fi * 4];
      float4 x1 = *(const float4*)&x[(size_t)e1.x * F_IN + fi * 4];
      float v0 = __int_as_float(e0.y), v1 = __int_as_float(e1.y);
      ax += v0 * x0.x; ay += v0 * x0.y; az += v0 * x0.z; aw += v0 * x0.w;
      ax += v1 * x1.x; ay += v1 * x1.y; az += v1 * x1.z; aw += v1 * x1.w;
    }
    for (; j + 4 <= j1; j += 4) {
      int2 e = epack[j + h];
      float4 xx = *(const float4*)&x[(size_t)e.x * F_IN + fi * 4];
      float v = __int_as_float(e.y);
      ax += v * xx.x; ay += v * xx.y; az += v * xx.z; aw += v * xx.w;
    }
    int rem = j1 - j;                 // 0..3
    if (h < rem) {
      int2 e = epack[j + h];
      float4 xx = *(const float4*)&x[(size_t)e.x * F_IN + fi * 4];
      float v = __int_as_float(e.y);
      ax += v * xx.x; ay += v * xx.y; az += v * xx.z; aw += v * xx.w;
    }
    // reduce over the 4 edge-groups (h): xor 16 then xor 32
    ax += __shfl_xor(ax, 16, 64); ay += __shfl_xor(ay, 16, 64);
    az += __shfl_xor(az, 16, 64); aw += __shfl_xor(aw, 16, 64);
    ax += __shfl_xor(ax, 32, 64); ay += __shfl_xor(ay, 32, 64);
    az += __shfl_xor(az, 32, 64); aw += __shfl_xor(aw, 32, 64);
    if (lane < 16) {
      float4 o; o.x = ax; o.y = ay; o.z = az; o.w = aw;
      *(float4*)&sX[(wid * 4 + r) * F_IN + fi * 4] = o;
    }
  }
  __syncthreads();

  // phase 1: sH = relu(sX @ W1); W1 streamed from global (L1/L2-resident).
  {
    int c = tid & 127;
    int r0 = (tid >> 7) * 8;
    float acc[8];
#pragma unroll
    for (int i = 0; i < 8; ++i) acc[i] = 0.f;
    for (int k = 0; k < F_IN; ++k) {
      float w = W1[k * F_HID + c];
#pragma unroll
      for (int i = 0; i < 8; ++i) acc[i] += sX[(r0 + i) * F_IN + k] * w;
    }
#pragma unroll
    for (int i = 0; i < 8; ++i) sH[(r0 + i) * SHP + c] = fmaxf(acc[i], 0.f);
  }
  __syncthreads();

  // phase 2: g = sH @ W2; W2 from global. Padded sH → no bank conflicts.
  for (int o = tid; o < 32 * F_OUT; o += 512) {
    int r = o / F_OUT, c = o - r * F_OUT;
    float acc = 0.f;
    for (int k = 0; k < F_HID; ++k)
      acc += sH[r * SHP + k] * W2[k * F_OUT + c];
    g[(size_t)(rbase + r) * F_OUT + c] = acc;
  }
}

// ------- SPMM2 gather: out = A @ g (40 feats = 10 lanes x float4) -------
// 6 edge-groups (60 lanes), 6 edges/step, unroll x2 = 12 in flight.
__global__ __launch_bounds__(256) void spmm2_kernel(
    const int* __restrict__ rs, const int2* __restrict__ epack,
    const float* __restrict__ g, float* __restrict__ out) {
  int node = (blockIdx.x * 256 + threadIdx.x) >> 6;
  int lane = threadIdx.x & 63;
  if (node >= N_NODES) return;
  int grp = lane / 10;        // 0..5 live, 6 = idle (lanes 60-63)
  int fi = lane % 10;         // feature quad (feats 4fi..4fi+3)
  bool active = grp < 6;
  int j0 = rs[node], j1 = rs[node + 1];
  float ax = 0.f, ay = 0.f, az = 0.f, aw = 0.f;
  int j = j0;
  for (; j + 12 <= j1; j += 12) {   // 12 edges in flight
    if (active) {
      int2 ea = epack[j + grp];
      int2 eb = epack[j + 6 + grp];
      float4 ga = *(const float4*)&g[(size_t)ea.x * F_OUT + fi * 4];
      float4 gb = *(const float4*)&g[(size_t)eb.x * F_OUT + fi * 4];
      float va = __int_as_float(ea.y), vb = __int_as_float(eb.y);
      ax += va * ga.x; ay += va * ga.y; az += va * ga.z; aw += va * ga.w;
      ax += vb * gb.x; ay += vb * gb.y; az += vb * gb.z; aw += vb * gb.w;
    }
  }
  for (; j + 6 <= j1; j += 6) {
    if (active) {
      int2 e = epack[j + grp];
      float4 gg = *(const float4*)&g[(size_t)e.x * F_OUT + fi * 4];
      float v = __int_as_float(e.y);
      ax += v * gg.x; ay += v * gg.y; az += v * gg.z; aw += v * gg.w;
    }
  }
  int rem = j1 - j;                 // 0..5
  if (grp < rem) {
    int2 e = epack[j + grp];
    float4 gg = *(const float4*)&g[(size_t)e.x * F_OUT + fi * 4];
    float v = __int_as_float(e.y);
    ax += v * gg.x; ay += v * gg.y; az += v * gg.z; aw += v * gg.w;
  }
  // merge 6 groups: lanes 0-29 += lanes 30-59; lanes 0-9 += lanes 10-19,20-29
  float tx = __shfl(ax, lane + 30, 64), ty = __shfl(ay, lane + 30, 64);
  float tz = __shfl(az, lane + 30, 64), tw = __shfl(aw, lane + 30, 64);
  if (lane < 30) { ax += tx; ay += ty; az += tz; aw += tw; }
  float ux = __shfl(ax, lane + 10, 64), uy = __shfl(ay, lane + 10, 64);
  float uz = __shfl(az, lane + 10, 64), uw = __shfl(aw, lane + 10, 64);
  float vx = __shfl(ax, lane + 20, 64), vy = __shfl(ay, lane + 20, 64);
  float vz = __shfl(az, lane + 20, 64), vw = __shfl(aw, lane + 20, 64);
  if (lane < 10) {
    ax += ux + vx; ay += uy + vy; az += uz + vz; aw += uw + vw;
    float4 o; o.x = ax; o.y = ay; o.z = az; o.w = aw;
    *(float4*)&out[(size_t)node * F_OUT + fi * 4] = o;
  }
}

extern "C" void kernel_launch(void* const* d_in, const int* in_sizes, int n_in,
                              void* d_out, int out_size, void* d_ws, size_t ws_size,
                              hipStream_t stream) {
  const int* src = (const int*)d_in[0];
  const int* dst = (const int*)d_in[1];
  const float* vals = (const float*)d_in[2];
  const float* x = (const float*)d_in[3];
  const float* W1 = (const float*)d_in[4];
  const float* W2 = (const float*)d_in[5];
  float* out = (float*)d_out;

  // 16B-aligned layout (int offsets)
  int* deg = (int*)d_ws;                         // [0, 80000)
  int* rs = deg + 80000;                         // [80000, 160004) (80001 used, pad to 80004)
  int* cur = rs + 80004;                         // [160004, 240004)
  int2* epack = (int2*)(cur + 80000);            // 960016 B offset, 8B aligned
  float* g = (float*)(epack + N_EDGES);          // 3.2M floats
  int* bsum = (int*)(g + (size_t)N_NODES * F_OUT);  // 20
  int* boff = bsum + 32;                         // 20

  hipMemsetAsync(deg, 0, N_NODES * sizeof(int), stream);

  hist_kernel<<<(N_EDGES + 255) / 256, 256, 0, stream>>>(src, deg);
  scanA_kernel<<<20, 1024, 0, stream>>>((const int4*)deg, (int4*)rs, bsum);
  scanB_kernel<<<1, 64, 0, stream>>>(bsum, boff, rs);
  scanC_kernel<<<20, 1024, 0, stream>>>((int4*)rs, (int4*)cur, boff);
  scatter_kernel<<<(N_EDGES + 255) / 256, 256, 0, stream>>>(src, dst, vals, cur, epack);
  spmm_dense_kernel<<<N_NODES / 32, 512, 0, stream>>>(rs, epack, x, W1, W2, g);
  spmm2_kernel<<<(N_NODES * 64 + 255) / 256, 256, 0, stream>>>(rs, epack, g, out);
}

// Round 9
// 301.728 us; speedup vs baseline: 1.9823x; 1.0090x over previous
//
#include <hip/hip_runtime.h>

#define N_NODES 80000
#define N_EDGES 1280000
#define F_IN 64
#define F_HID 128
#define F_OUT 40
#define NQ (N_NODES / 4)   // 20000 int4 groups
#define SHP 132            // padded sH stride: 16B-aligned float4 rows, banks (4r+k)%32

// ---------------- CSR build: histogram ----------------
__global__ __launch_bounds__(256) void hist_kernel(const int* __restrict__ src,
                                                   int* __restrict__ deg) {
  int i = blockIdx.x * 256 + threadIdx.x;
  if (i < N_EDGES) atomicAdd(&deg[src[i]], 1);
}

// ------- scan A: 20 blocks, block-local exclusive scan + block sums -------
__global__ __launch_bounds__(1024) void scanA_kernel(const int4* __restrict__ deg4,
                                                     int4* __restrict__ rs4,
                                                     int* __restrict__ bsum) {
  __shared__ int wsum[16];
  __shared__ int woff[16];
  int tid = threadIdx.x, lane = tid & 63, wid = tid >> 6;
  int i = blockIdx.x * 1024 + tid;
  int4 v = (i < NQ) ? deg4[i] : make_int4(0, 0, 0, 0);
  int tot = v.x + v.y + v.z + v.w;
  int s = tot;
#pragma unroll
  for (int off = 1; off < 64; off <<= 1) {
    int t = __shfl_up(s, off, 64);
    if (lane >= off) s += t;
  }
  if (lane == 63) wsum[wid] = s;
  __syncthreads();
  if (wid == 0) {
    int wv = (lane < 16) ? wsum[lane] : 0;
    int ss = wv;
#pragma unroll
    for (int off = 1; off < 16; off <<= 1) {
      int t = __shfl_up(ss, off, 64);
      if (lane >= off) ss += t;
    }
    if (lane < 16) woff[lane] = ss - wv;
    if (lane == 15) bsum[blockIdx.x] = ss;
  }
  __syncthreads();
  int excl = woff[wid] + (s - tot);
  if (i < NQ) {
    int e0 = excl, e1 = e0 + v.x, e2 = e1 + v.y, e3 = e2 + v.z;
    rs4[i] = make_int4(e0, e1, e2, e3);
  }
}

// ------- scan B: 1 tiny block scans the 20 block sums -------
__global__ __launch_bounds__(64) void scanB_kernel(const int* __restrict__ bsum,
                                                   int* __restrict__ boff,
                                                   int* __restrict__ rs) {
  int lane = threadIdx.x;
  int v = (lane < 20) ? bsum[lane] : 0;
  int s = v;
#pragma unroll
  for (int off = 1; off < 32; off <<= 1) {
    int t = __shfl_up(s, off, 64);
    if (lane >= off) s += t;
  }
  if (lane < 20) boff[lane] = s - v;
  if (lane == 19) rs[N_NODES] = s;   // grand total
}

// ------- scan C: add block offsets, write rs and cur -------
__global__ __launch_bounds__(1024) void scanC_kernel(int4* __restrict__ rs4,
                                                     int4* __restrict__ cur4,
                                                     const int* __restrict__ boff) {
  int i = blockIdx.x * 1024 + threadIdx.x;
  if (i < NQ) {
    int o = boff[blockIdx.x];
    int4 r = rs4[i];
    r.x += o; r.y += o; r.z += o; r.w += o;
    rs4[i] = r;
    cur4[i] = r;
  }
}

// ---------------- CSR build: scatter packed (dst,val) ----------------
__global__ __launch_bounds__(256) void scatter_kernel(
    const int* __restrict__ src, const int* __restrict__ dst,
    const float* __restrict__ vals, int* __restrict__ cur,
    int2* __restrict__ epack) {
  int i = blockIdx.x * 256 + threadIdx.x;
  if (i < N_EDGES) {
    int p = atomicAdd(&cur[src[i]], 1);
    epack[p] = make_int2(dst[i], __float_as_int(vals[i]));
  }
}

// ---- Fused: rows = gather(A, x) in LDS, then g = relu(rows@W1)@W2 ----
// 512 threads = 8 waves; 32 rows/block; wave gathers 4 rows.
__global__ __launch_bounds__(512, 6) void spmm_dense_kernel(
    const int* __restrict__ rs, const int2* __restrict__ epack,
    const float* __restrict__ x, const float* __restrict__ W1,
    const float* __restrict__ W2, float* __restrict__ g) {
  __shared__ float sX[32 * F_IN];     // 8 KB
  __shared__ float sH[32 * SHP];      // 16.5 KB (padded)
  int tid = threadIdx.x, lane = tid & 63, wid = tid >> 6;
  int rbase = blockIdx.x * 32;
  int h = lane >> 4;     // 0..3: which of 4 parallel edges
  int fi = lane & 15;    // feature-quad index (feats 4fi..4fi+3)

#pragma unroll
  for (int r = 0; r < 4; ++r) {
    int node = rbase + wid * 4 + r;
    int j0 = rs[node], j1 = rs[node + 1];
    float ax = 0.f, ay = 0.f, az = 0.f, aw = 0.f;
    int j = j0;
    for (; j + 8 <= j1; j += 8) {     // 8 edges in flight
      int2 e0 = epack[j + h];
      int2 e1 = epack[j + 4 + h];
      float4 x0 = *(const float4*)&x[(size_t)e0.x * F_IN + fi * 4];
      float4 x1 = *(const float4*)&x[(size_t)e1.x * F_IN + fi * 4];
      float v0 = __int_as_float(e0.y), v1 = __int_as_float(e1.y);
      ax += v0 * x0.x; ay += v0 * x0.y; az += v0 * x0.z; aw += v0 * x0.w;
      ax += v1 * x1.x; ay += v1 * x1.y; az += v1 * x1.z; aw += v1 * x1.w;
    }
    for (; j + 4 <= j1; j += 4) {
      int2 e = epack[j + h];
      float4 xx = *(const float4*)&x[(size_t)e.x * F_IN + fi * 4];
      float v = __int_as_float(e.y);
      ax += v * xx.x; ay += v * xx.y; az += v * xx.z; aw += v * xx.w;
    }
    int rem = j1 - j;                 // 0..3
    if (h < rem) {
      int2 e = epack[j + h];
      float4 xx = *(const float4*)&x[(size_t)e.x * F_IN + fi * 4];
      float v = __int_as_float(e.y);
      ax += v * xx.x; ay += v * xx.y; az += v * xx.z; aw += v * xx.w;
    }
    // reduce over the 4 edge-groups (h): xor 16 then xor 32
    ax += __shfl_xor(ax, 16, 64); ay += __shfl_xor(ay, 16, 64);
    az += __shfl_xor(az, 16, 64); aw += __shfl_xor(aw, 16, 64);
    ax += __shfl_xor(ax, 32, 64); ay += __shfl_xor(ay, 32, 64);
    az += __shfl_xor(az, 32, 64); aw += __shfl_xor(aw, 32, 64);
    if (lane < 16) {
      float4 o; o.x = ax; o.y = ay; o.z = az; o.w = aw;
      *(float4*)&sX[(wid * 4 + r) * F_IN + fi * 4] = o;
    }
  }
  __syncthreads();

  // phase 1: sH = relu(sX @ W1). k-blocked x4: 8 ds_read_b128 (wave-uniform
  // broadcast) + 4 scalar W1 loads per 32 FMAs.
  {
    int c = tid & 127;
    int r0 = (tid >> 7) * 8;   // 0,8,16,24
    float acc[8];
#pragma unroll
    for (int i = 0; i < 8; ++i) acc[i] = 0.f;
    const float4* sX4 = (const float4*)sX;
    for (int k = 0; k < F_IN; k += 4) {
      float4 xq[8];
#pragma unroll
      for (int i = 0; i < 8; ++i) xq[i] = sX4[((r0 + i) * F_IN + k) >> 2];
      float w0 = W1[(k + 0) * F_HID + c];
      float w1 = W1[(k + 1) * F_HID + c];
      float w2 = W1[(k + 2) * F_HID + c];
      float w3 = W1[(k + 3) * F_HID + c];
#pragma unroll
      for (int i = 0; i < 8; ++i)
        acc[i] += xq[i].x * w0 + xq[i].y * w1 + xq[i].z * w2 + xq[i].w * w3;
    }
#pragma unroll
    for (int i = 0; i < 8; ++i) sH[(r0 + i) * SHP + c] = fmaxf(acc[i], 0.f);
  }
  __syncthreads();

  // phase 2: g = sH @ W2. 320 active threads (5 waves): thread = (row, colquad).
  if (tid < 320) {
    int r = tid / 10;          // 0..31
    int cg = tid - r * 10;     // 0..9 -> cols 4cg..4cg+3
    float4 acc = make_float4(0.f, 0.f, 0.f, 0.f);
    for (int k = 0; k < F_HID; k += 4) {
      float4 hq = *(const float4*)&sH[r * SHP + k];
      float4 w0 = *(const float4*)&W2[(k + 0) * F_OUT + cg * 4];
      float4 w1 = *(const float4*)&W2[(k + 1) * F_OUT + cg * 4];
      float4 w2 = *(const float4*)&W2[(k + 2) * F_OUT + cg * 4];
      float4 w3 = *(const float4*)&W2[(k + 3) * F_OUT + cg * 4];
      acc.x += hq.x * w0.x + hq.y * w1.x + hq.z * w2.x + hq.w * w3.x;
      acc.y += hq.x * w0.y + hq.y * w1.y + hq.z * w2.y + hq.w * w3.y;
      acc.z += hq.x * w0.z + hq.y * w1.z + hq.z * w2.z + hq.w * w3.z;
      acc.w += hq.x * w0.w + hq.y * w1.w + hq.z * w2.w + hq.w * w3.w;
    }
    *(float4*)&g[(size_t)(rbase + r) * F_OUT + cg * 4] = acc;
  }
}

// ------- SPMM2 gather: out = A @ g (40 feats = 10 lanes x float4) -------
// 6 edge-groups (60 lanes), 6 edges/step, unroll x2 = 12 in flight.
__global__ __launch_bounds__(256) void spmm2_kernel(
    const int* __restrict__ rs, const int2* __restrict__ epack,
    const float* __restrict__ g, float* __restrict__ out) {
  int node = (blockIdx.x * 256 + threadIdx.x) >> 6;
  int lane = threadIdx.x & 63;
  if (node >= N_NODES) return;
  int grp = lane / 10;        // 0..5 live, 6 = idle (lanes 60-63)
  int fi = lane % 10;         // feature quad (feats 4fi..4fi+3)
  bool active = grp < 6;
  int j0 = rs[node], j1 = rs[node + 1];
  float ax = 0.f, ay = 0.f, az = 0.f, aw = 0.f;
  int j = j0;
  for (; j + 12 <= j1; j += 12) {   // 12 edges in flight
    if (active) {
      int2 ea = epack[j + grp];
      int2 eb = epack[j + 6 + grp];
      float4 ga = *(const float4*)&g[(size_t)ea.x * F_OUT + fi * 4];
      float4 gb = *(const float4*)&g[(size_t)eb.x * F_OUT + fi * 4];
      float va = __int_as_float(ea.y), vb = __int_as_float(eb.y);
      ax += va * ga.x; ay += va * ga.y; az += va * ga.z; aw += va * ga.w;
      ax += vb * gb.x; ay += vb * gb.y; az += vb * gb.z; aw += vb * gb.w;
    }
  }
  for (; j + 6 <= j1; j += 6) {
    if (active) {
      int2 e = epack[j + grp];
      float4 gg = *(const float4*)&g[(size_t)e.x * F_OUT + fi * 4];
      float v = __int_as_float(e.y);
      ax += v * gg.x; ay += v * gg.y; az += v * gg.z; aw += v * gg.w;
    }
  }
  int rem = j1 - j;                 // 0..5
  if (grp < rem) {
    int2 e = epack[j + grp];
    float4 gg = *(const float4*)&g[(size_t)e.x * F_OUT + fi * 4];
    float v = __int_as_float(e.y);
    ax += v * gg.x; ay += v * gg.y; az += v * gg.z; aw += v * gg.w;
  }
  // merge 6 groups: lanes 0-29 += lanes 30-59; lanes 0-9 += lanes 10-19,20-29
  float tx = __shfl(ax, lane + 30, 64), ty = __shfl(ay, lane + 30, 64);
  float tz = __shfl(az, lane + 30, 64), tw = __shfl(aw, lane + 30, 64);
  if (lane < 30) { ax += tx; ay += ty; az += tz; aw += tw; }
  float ux = __shfl(ax, lane + 10, 64), uy = __shfl(ay, lane + 10, 64);
  float uz = __shfl(az, lane + 10, 64), uw = __shfl(aw, lane + 10, 64);
  float vx = __shfl(ax, lane + 20, 64), vy = __shfl(ay, lane + 20, 64);
  float vz = __shfl(az, lane + 20, 64), vw = __shfl(aw, lane + 20, 64);
  if (lane < 10) {
    ax += ux + vx; ay += uy + vy; az += uz + vz; aw += uw + vw;
    float4 o; o.x = ax; o.y = ay; o.z = az; o.w = aw;
    *(float4*)&out[(size_t)node * F_OUT + fi * 4] = o;
  }
}

extern "C" void kernel_launch(void* const* d_in, const int* in_sizes, int n_in,
                              void* d_out, int out_size, void* d_ws, size_t ws_size,
                              hipStream_t stream) {
  const int* src = (const int*)d_in[0];
  const int* dst = (const int*)d_in[1];
  const float* vals = (const float*)d_in[2];
  const float* x = (const float*)d_in[3];
  const float* W1 = (const float*)d_in[4];
  const float* W2 = (const float*)d_in[5];
  float* out = (float*)d_out;

  // 16B-aligned layout (int offsets)
  int* deg = (int*)d_ws;                         // [0, 80000)
  int* rs = deg + 80000;                         // 80001 used, pad to 80004
  int* cur = rs + 80004;                         // 80000
  int2* epack = (int2*)(cur + 80000);            // 960016 B offset, 16B aligned
  float* g = (float*)(epack + N_EDGES);          // 3.2M floats
  int* bsum = (int*)(g + (size_t)N_NODES * F_OUT);  // 20
  int* boff = bsum + 32;                         // 20

  hipMemsetAsync(deg, 0, N_NODES * sizeof(int), stream);

  hist_kernel<<<(N_EDGES + 255) / 256, 256, 0, stream>>>(src, deg);
  scanA_kernel<<<20, 1024, 0, stream>>>((const int4*)deg, (int4*)rs, bsum);
  scanB_kernel<<<1, 64, 0, stream>>>(bsum, boff, rs);
  scanC_kernel<<<20, 1024, 0, stream>>>((int4*)rs, (int4*)cur, boff);
  scatter_kernel<<<(N_EDGES + 255) / 256, 256, 0, stream>>>(src, dst, vals, cur, epack);
  spmm_dense_kernel<<<N_NODES / 32, 512, 0, stream>>>(rs, epack, x, W1, W2, g);
  spmm2_kernel<<<(N_NODES * 64 + 255) / 256, 256, 0, stream>>>(rs, epack, g, out);
}

// Round 10
// 284.705 us; speedup vs baseline: 2.1009x; 1.0598x over previous
//
#include <hip/hip_runtime.h>

#define N_NODES 80000
#define N_EDGES 1280000
#define F_IN 64
#define F_HID 128
#define F_OUT 40
#define NQ (N_NODES / 4)   // 20000 int4 groups
#define SHP 132            // padded sH stride: 16B-aligned float4 rows

__device__ __forceinline__ unsigned short bf16rn(float f) {
  unsigned u = __float_as_uint(f);
  u += 0x7fffu + ((u >> 16) & 1u);   // round-to-nearest-even
  return (unsigned short)(u >> 16);
}
__device__ __forceinline__ float bflo(unsigned w) { return __uint_as_float(w << 16); }
__device__ __forceinline__ float bfhi(unsigned w) { return __uint_as_float(w & 0xffff0000u); }

// ---------------- x -> bf16 conversion ----------------
__global__ __launch_bounds__(256) void xcvt_kernel(const float4* __restrict__ x4,
                                                   ushort4* __restrict__ xb4) {
  int i = blockIdx.x * 256 + threadIdx.x;
  if (i < N_NODES * F_IN / 4) {
    float4 v = x4[i];
    ushort4 o;
    o.x = bf16rn(v.x); o.y = bf16rn(v.y); o.z = bf16rn(v.z); o.w = bf16rn(v.w);
    xb4[i] = o;
  }
}

// ---------------- CSR build: histogram ----------------
__global__ __launch_bounds__(256) void hist_kernel(const int* __restrict__ src,
                                                   int* __restrict__ deg) {
  int i = blockIdx.x * 256 + threadIdx.x;
  if (i < N_EDGES) atomicAdd(&deg[src[i]], 1);
}

// ------- scan A: 20 blocks, block-local exclusive scan + block sums -------
__global__ __launch_bounds__(1024) void scanA_kernel(const int4* __restrict__ deg4,
                                                     int4* __restrict__ rs4,
                                                     int* __restrict__ bsum) {
  __shared__ int wsum[16];
  __shared__ int woff[16];
  int tid = threadIdx.x, lane = tid & 63, wid = tid >> 6;
  int i = blockIdx.x * 1024 + tid;
  int4 v = (i < NQ) ? deg4[i] : make_int4(0, 0, 0, 0);
  int tot = v.x + v.y + v.z + v.w;
  int s = tot;
#pragma unroll
  for (int off = 1; off < 64; off <<= 1) {
    int t = __shfl_up(s, off, 64);
    if (lane >= off) s += t;
  }
  if (lane == 63) wsum[wid] = s;
  __syncthreads();
  if (wid == 0) {
    int wv = (lane < 16) ? wsum[lane] : 0;
    int ss = wv;
#pragma unroll
    for (int off = 1; off < 16; off <<= 1) {
      int t = __shfl_up(ss, off, 64);
      if (lane >= off) ss += t;
    }
    if (lane < 16) woff[lane] = ss - wv;
    if (lane == 15) bsum[blockIdx.x] = ss;
  }
  __syncthreads();
  int excl = woff[wid] + (s - tot);
  if (i < NQ) {
    int e0 = excl, e1 = e0 + v.x, e2 = e1 + v.y, e3 = e2 + v.z;
    rs4[i] = make_int4(e0, e1, e2, e3);
  }
}

// ------- scan B: 1 tiny block scans the 20 block sums -------
__global__ __launch_bounds__(64) void scanB_kernel(const int* __restrict__ bsum,
                                                   int* __restrict__ boff,
                                                   int* __restrict__ rs) {
  int lane = threadIdx.x;
  int v = (lane < 20) ? bsum[lane] : 0;
  int s = v;
#pragma unroll
  for (int off = 1; off < 32; off <<= 1) {
    int t = __shfl_up(s, off, 64);
    if (lane >= off) s += t;
  }
  if (lane < 20) boff[lane] = s - v;
  if (lane == 19) rs[N_NODES] = s;   // grand total
}

// ------- scan C: add block offsets, write rs and cur -------
__global__ __launch_bounds__(1024) void scanC_kernel(int4* __restrict__ rs4,
                                                     int4* __restrict__ cur4,
                                                     const int* __restrict__ boff) {
  int i = blockIdx.x * 1024 + threadIdx.x;
  if (i < NQ) {
    int o = boff[blockIdx.x];
    int4 r = rs4[i];
    r.x += o; r.y += o; r.z += o; r.w += o;
    rs4[i] = r;
    cur4[i] = r;
  }
}

// ---------------- CSR build: scatter packed (dst,val) ----------------
__global__ __launch_bounds__(256) void scatter_kernel(
    const int* __restrict__ src, const int* __restrict__ dst,
    const float* __restrict__ vals, int* __restrict__ cur,
    int2* __restrict__ epack) {
  int i = blockIdx.x * 256 + threadIdx.x;
  if (i < N_EDGES) {
    int p = atomicAdd(&cur[src[i]], 1);
    epack[p] = make_int2(dst[i], __float_as_int(vals[i]));
  }
}

// ---- Fused: rows = gather(A, xb) in LDS, then g = relu(rows@W1)@W2 (bf16 out)
// 512 threads = 8 waves; 32 rows/block; wave gathers 4 rows.
// Gather lanes: fi = lane&7 (uint4 = 8 bf16 feats), h = lane>>3 (8 edges/step).
__global__ __launch_bounds__(512, 6) void spmm_dense_kernel(
    const int* __restrict__ rs, const int2* __restrict__ epack,
    const uint4* __restrict__ xb, const float* __restrict__ W1,
    const float* __restrict__ W2, unsigned short* __restrict__ gb) {
  __shared__ float sX[32 * F_IN];     // 8 KB
  __shared__ float sH[32 * SHP];      // 16.5 KB (padded)
  int tid = threadIdx.x, lane = tid & 63, wid = tid >> 6;
  int rbase = blockIdx.x * 32;
  int h = lane >> 3;     // 0..7: which of 8 parallel edges
  int fi = lane & 7;     // feature-oct index (feats 8fi..8fi+7)

#pragma unroll
  for (int r = 0; r < 4; ++r) {
    int node = rbase + wid * 4 + r;
    int j0 = rs[node], j1 = rs[node + 1];
    float a0 = 0.f, a1 = 0.f, a2 = 0.f, a3 = 0.f;
    float a4 = 0.f, a5 = 0.f, a6 = 0.f, a7 = 0.f;
    int j = j0;
    for (; j + 16 <= j1; j += 16) {   // 16 edges in flight
      int2 e0 = epack[j + h];
      int2 e1 = epack[j + 8 + h];
      uint4 q0 = xb[(size_t)e0.x * 8 + fi];
      uint4 q1 = xb[(size_t)e1.x * 8 + fi];
      float v0 = __int_as_float(e0.y), v1 = __int_as_float(e1.y);
      a0 += v0 * bflo(q0.x); a1 += v0 * bfhi(q0.x);
      a2 += v0 * bflo(q0.y); a3 += v0 * bfhi(q0.y);
      a4 += v0 * bflo(q0.z); a5 += v0 * bfhi(q0.z);
      a6 += v0 * bflo(q0.w); a7 += v0 * bfhi(q0.w);
      a0 += v1 * bflo(q1.x); a1 += v1 * bfhi(q1.x);
      a2 += v1 * bflo(q1.y); a3 += v1 * bfhi(q1.y);
      a4 += v1 * bflo(q1.z); a5 += v1 * bfhi(q1.z);
      a6 += v1 * bflo(q1.w); a7 += v1 * bfhi(q1.w);
    }
    for (; j + 8 <= j1; j += 8) {
      int2 e = epack[j + h];
      uint4 q = xb[(size_t)e.x * 8 + fi];
      float v = __int_as_float(e.y);
      a0 += v * bflo(q.x); a1 += v * bfhi(q.x);
      a2 += v * bflo(q.y); a3 += v * bfhi(q.y);
      a4 += v * bflo(q.z); a5 += v * bfhi(q.z);
      a6 += v * bflo(q.w); a7 += v * bfhi(q.w);
    }
    if (h < j1 - j) {                 // tail 0..7 edges
      int2 e = epack[j + h];
      uint4 q = xb[(size_t)e.x * 8 + fi];
      float v = __int_as_float(e.y);
      a0 += v * bflo(q.x); a1 += v * bfhi(q.x);
      a2 += v * bflo(q.y); a3 += v * bfhi(q.y);
      a4 += v * bflo(q.z); a5 += v * bfhi(q.z);
      a6 += v * bflo(q.w); a7 += v * bfhi(q.w);
    }
    // reduce over 8 edge-groups: xor 8, 16, 32
#pragma unroll
    for (int m = 8; m <= 32; m <<= 1) {
      a0 += __shfl_xor(a0, m, 64); a1 += __shfl_xor(a1, m, 64);
      a2 += __shfl_xor(a2, m, 64); a3 += __shfl_xor(a3, m, 64);
      a4 += __shfl_xor(a4, m, 64); a5 += __shfl_xor(a5, m, 64);
      a6 += __shfl_xor(a6, m, 64); a7 += __shfl_xor(a7, m, 64);
    }
    if (lane < 8) {
      float4 o0; o0.x = a0; o0.y = a1; o0.z = a2; o0.w = a3;
      float4 o1; o1.x = a4; o1.y = a5; o1.z = a6; o1.w = a7;
      *(float4*)&sX[(wid * 4 + r) * F_IN + fi * 8] = o0;
      *(float4*)&sX[(wid * 4 + r) * F_IN + fi * 8 + 4] = o1;
    }
  }
  __syncthreads();

  // phase 1: sH = relu(sX @ W1). k-blocked x4 with ds_read_b128 broadcasts.
  {
    int c = tid & 127;
    int r0 = (tid >> 7) * 8;   // 0,8,16,24
    float acc[8];
#pragma unroll
    for (int i = 0; i < 8; ++i) acc[i] = 0.f;
    const float4* sX4 = (const float4*)sX;
    for (int k = 0; k < F_IN; k += 4) {
      float4 xq[8];
#pragma unroll
      for (int i = 0; i < 8; ++i) xq[i] = sX4[((r0 + i) * F_IN + k) >> 2];
      float w0 = W1[(k + 0) * F_HID + c];
      float w1 = W1[(k + 1) * F_HID + c];
      float w2 = W1[(k + 2) * F_HID + c];
      float w3 = W1[(k + 3) * F_HID + c];
#pragma unroll
      for (int i = 0; i < 8; ++i)
        acc[i] += xq[i].x * w0 + xq[i].y * w1 + xq[i].z * w2 + xq[i].w * w3;
    }
#pragma unroll
    for (int i = 0; i < 8; ++i) sH[(r0 + i) * SHP + c] = fmaxf(acc[i], 0.f);
  }
  __syncthreads();

  // phase 2: gb = bf16(sH @ W2). 320 active threads: thread = (row, colquad).
  if (tid < 320) {
    int r = tid / 10;          // 0..31
    int cg = tid - r * 10;     // 0..9 -> cols 4cg..4cg+3
    float4 acc = make_float4(0.f, 0.f, 0.f, 0.f);
    for (int k = 0; k < F_HID; k += 4) {
      float4 hq = *(const float4*)&sH[r * SHP + k];
      float4 w0 = *(const float4*)&W2[(k + 0) * F_OUT + cg * 4];
      float4 w1 = *(const float4*)&W2[(k + 1) * F_OUT + cg * 4];
      float4 w2 = *(const float4*)&W2[(k + 2) * F_OUT + cg * 4];
      float4 w3 = *(const float4*)&W2[(k + 3) * F_OUT + cg * 4];
      acc.x += hq.x * w0.x + hq.y * w1.x + hq.z * w2.x + hq.w * w3.x;
      acc.y += hq.x * w0.y + hq.y * w1.y + hq.z * w2.y + hq.w * w3.y;
      acc.z += hq.x * w0.z + hq.y * w1.z + hq.z * w2.z + hq.w * w3.z;
      acc.w += hq.x * w0.w + hq.y * w1.w + hq.z * w2.w + hq.w * w3.w;
    }
    ushort4 ob;
    ob.x = bf16rn(acc.x); ob.y = bf16rn(acc.y);
    ob.z = bf16rn(acc.z); ob.w = bf16rn(acc.w);
    *(ushort4*)&gb[(size_t)(rbase + r) * F_OUT + cg * 4] = ob;
  }
}

// ------- SPMM2 gather: out = A @ gb (40 bf16 feats = 5 lanes x uint4) -------
// 12 edge-groups (60 lanes), 12 edges/step, unroll x2 = 24 in flight.
__global__ __launch_bounds__(256) void spmm2_kernel(
    const int* __restrict__ rs, const int2* __restrict__ epack,
    const uint4* __restrict__ gb4, float* __restrict__ out) {
  int node = (blockIdx.x * 256 + threadIdx.x) >> 6;
  int lane = threadIdx.x & 63;
  if (node >= N_NODES) return;
  int grp = lane / 5;         // 0..11 live, 12 = idle (lanes 60-63)
  int fi = lane % 5;          // feature oct (feats 8fi..8fi+7)
  bool active = grp < 12;
  int j0 = rs[node], j1 = rs[node + 1];
  float a0 = 0.f, a1 = 0.f, a2 = 0.f, a3 = 0.f;
  float a4 = 0.f, a5 = 0.f, a6 = 0.f, a7 = 0.f;
  int j = j0;
  for (; j + 24 <= j1; j += 24) {   // 24 edges in flight
    if (active) {
      int2 e0 = epack[j + grp];
      int2 e1 = epack[j + 12 + grp];
      uint4 q0 = gb4[(size_t)e0.x * 5 + fi];
      uint4 q1 = gb4[(size_t)e1.x * 5 + fi];
      float v0 = __int_as_float(e0.y), v1 = __int_as_float(e1.y);
      a0 += v0 * bflo(q0.x); a1 += v0 * bfhi(q0.x);
      a2 += v0 * bflo(q0.y); a3 += v0 * bfhi(q0.y);
      a4 += v0 * bflo(q0.z); a5 += v0 * bfhi(q0.z);
      a6 += v0 * bflo(q0.w); a7 += v0 * bfhi(q0.w);
      a0 += v1 * bflo(q1.x); a1 += v1 * bfhi(q1.x);
      a2 += v1 * bflo(q1.y); a3 += v1 * bfhi(q1.y);
      a4 += v1 * bflo(q1.z); a5 += v1 * bfhi(q1.z);
      a6 += v1 * bflo(q1.w); a7 += v1 * bfhi(q1.w);
    }
  }
  for (; j + 12 <= j1; j += 12) {
    if (active) {
      int2 e = epack[j + grp];
      uint4 q = gb4[(size_t)e.x * 5 + fi];
      float v = __int_as_float(e.y);
      a0 += v * bflo(q.x); a1 += v * bfhi(q.x);
      a2 += v * bflo(q.y); a3 += v * bfhi(q.y);
      a4 += v * bflo(q.z); a5 += v * bfhi(q.z);
      a6 += v * bflo(q.w); a7 += v * bfhi(q.w);
    }
  }
  if (active && grp < j1 - j) {     // tail 0..11 edges
    int2 e = epack[j + grp];
    uint4 q = gb4[(size_t)e.x * 5 + fi];
    float v = __int_as_float(e.y);
    a0 += v * bflo(q.x); a1 += v * bfhi(q.x);
    a2 += v * bflo(q.y); a3 += v * bfhi(q.y);
    a4 += v * bflo(q.z); a5 += v * bfhi(q.z);
    a6 += v * bflo(q.w); a7 += v * bfhi(q.w);
  }
  // merge 12 groups of 5 lanes: +30, +15, then +5 and +10
  float t0, t1, t2, t3, t4, t5, t6, t7;
  t0 = __shfl(a0, lane + 30, 64); t1 = __shfl(a1, lane + 30, 64);
  t2 = __shfl(a2, lane + 30, 64); t3 = __shfl(a3, lane + 30, 64);
  t4 = __shfl(a4, lane + 30, 64); t5 = __shfl(a5, lane + 30, 64);
  t6 = __shfl(a6, lane + 30, 64); t7 = __shfl(a7, lane + 30, 64);
  if (lane < 30) { a0 += t0; a1 += t1; a2 += t2; a3 += t3;
                   a4 += t4; a5 += t5; a6 += t6; a7 += t7; }
  t0 = __shfl(a0, lane + 15, 64); t1 = __shfl(a1, lane + 15, 64);
  t2 = __shfl(a2, lane + 15, 64); t3 = __shfl(a3, lane + 15, 64);
  t4 = __shfl(a4, lane + 15, 64); t5 = __shfl(a5, lane + 15, 64);
  t6 = __shfl(a6, lane + 15, 64); t7 = __shfl(a7, lane + 15, 64);
  if (lane < 15) { a0 += t0; a1 += t1; a2 += t2; a3 += t3;
                   a4 += t4; a5 += t5; a6 += t6; a7 += t7; }
  float u0, u1, u2, u3, u4, u5, u6, u7;
  t0 = __shfl(a0, lane + 5, 64);  t1 = __shfl(a1, lane + 5, 64);
  t2 = __shfl(a2, lane + 5, 64);  t3 = __shfl(a3, lane + 5, 64);
  t4 = __shfl(a4, lane + 5, 64);  t5 = __shfl(a5, lane + 5, 64);
  t6 = __shfl(a6, lane + 5, 64);  t7 = __shfl(a7, lane + 5, 64);
  u0 = __shfl(a0, lane + 10, 64); u1 = __shfl(a1, lane + 10, 64);
  u2 = __shfl(a2, lane + 10, 64); u3 = __shfl(a3, lane + 10, 64);
  u4 = __shfl(a4, lane + 10, 64); u5 = __shfl(a5, lane + 10, 64);
  u6 = __shfl(a6, lane + 10, 64); u7 = __shfl(a7, lane + 10, 64);
  if (lane < 5) {
    a0 += t0 + u0; a1 += t1 + u1; a2 += t2 + u2; a3 += t3 + u3;
    a4 += t4 + u4; a5 += t5 + u5; a6 += t6 + u6; a7 += t7 + u7;
    float4 o0; o0.x = a0; o0.y = a1; o0.z = a2; o0.w = a3;
    float4 o1; o1.x = a4; o1.y = a5; o1.z = a6; o1.w = a7;
    *(float4*)&out[(size_t)node * F_OUT + fi * 8] = o0;
    *(float4*)&out[(size_t)node * F_OUT + fi * 8 + 4] = o1;
  }
}

extern "C" void kernel_launch(void* const* d_in, const int* in_sizes, int n_in,
                              void* d_out, int out_size, void* d_ws, size_t ws_size,
                              hipStream_t stream) {
  const int* src = (const int*)d_in[0];
  const int* dst = (const int*)d_in[1];
  const float* vals = (const float*)d_in[2];
  const float* x = (const float*)d_in[3];
  const float* W1 = (const float*)d_in[4];
  const float* W2 = (const float*)d_in[5];
  float* out = (float*)d_out;

  // 16B-aligned workspace layout
  int* deg = (int*)d_ws;                           // 80000 ints
  int* rs = deg + 80000;                           // 80001 used, pad to 80004
  int* cur = rs + 80004;                           // 80000
  int2* epack = (int2*)(cur + 80000);              // byte off 960016 (16B-aligned)
  unsigned short* xb = (unsigned short*)(epack + N_EDGES);   // 5.12M bf16 = 10.24 MB
  unsigned short* gb = xb + (size_t)N_NODES * F_IN;          // 3.2M bf16 = 6.4 MB
  int* bsum = (int*)(gb + (size_t)N_NODES * F_OUT);          // 20
  int* boff = bsum + 32;                                     // 20

  hipMemsetAsync(deg, 0, N_NODES * sizeof(int), stream);

  xcvt_kernel<<<(N_NODES * F_IN / 4 + 255) / 256, 256, 0, stream>>>(
      (const float4*)x, (ushort4*)xb);
  hist_kernel<<<(N_EDGES + 255) / 256, 256, 0, stream>>>(src, deg);
  scanA_kernel<<<20, 1024, 0, stream>>>((const int4*)deg, (int4*)rs, bsum);
  scanB_kernel<<<1, 64, 0, stream>>>(bsum, boff, rs);
  scanC_kernel<<<20, 1024, 0, stream>>>((int4*)rs, (int4*)cur, boff);
  scatter_kernel<<<(N_EDGES + 255) / 256, 256, 0, stream>>>(src, dst, vals, cur, epack);
  spmm_dense_kernel<<<N_NODES / 32, 512, 0, stream>>>(
      rs, epack, (const uint4*)xb, W1, W2, gb);
  spmm2_kernel<<<(N_NODES * 64 + 255) / 256, 256, 0, stream>>>(
      rs, epack, (const uint4*)gb, out);
}